// Round 11
// baseline (1022.647 us; speedup 1.0000x reference)
//
#include <hip/hip_runtime.h>
#include <hip/hip_fp16.h>

#define TT 1024
#define BB 256
#define II 128
#define HH 256

typedef _Float16 f16x8 __attribute__((ext_vector_type(8)));
typedef float    f32x4 __attribute__((ext_vector_type(4)));

union HU { _Float16 h[2]; unsigned u; };
static __device__ __forceinline__ unsigned pack2(float a, float b)
{
    HU t; t.h[0] = (_Float16)a; t.h[1] = (_Float16)b; return t.u;
}

// LDS-only barrier (keeps global stores/loads in flight across steps).
#define LDS_BARRIER()                                            \
    do {                                                         \
        asm volatile("s_waitcnt lgkmcnt(0)" ::: "memory");       \
        __builtin_amdgcn_s_barrier();                            \
        __builtin_amdgcn_sched_barrier(0);                       \
    } while (0)

// tanh(a) = 1 - 2/(2^(2a*log2e)+1)
__device__ __forceinline__ float fast_tanh(float a)
{
    float e = __builtin_amdgcn_exp2f(a * 2.8853900817779268f);
    return 1.0f - 2.0f * __builtin_amdgcn_rcpf(e + 1.0f);
}

static __device__ __forceinline__ f16x8 cvt8(const float* p)
{
    float4 a = *(const float4*)p;
    float4 b = *(const float4*)(p + 4);
    f16x8 r;
    r[0]=(_Float16)a.x; r[1]=(_Float16)a.y; r[2]=(_Float16)a.z; r[3]=(_Float16)a.w;
    r[4]=(_Float16)b.x; r[5]=(_Float16)b.y; r[6]=(_Float16)b.z; r[7]=(_Float16)b.w;
    return r;
}

// ---------------- Pre-GEMM: xw = x @ W^T  (fp32 out into seq region) --------
// M = T*B = 262144, K = 128, N = 256. 4096 WGs x 256 thr; wave wv owns rows
// 16wv..16wv+15 of a 64-row tile, all 256 cols. W staged in LDS as f16
// [256 cols][128 k] with XOR (col&7)<<4 swizzle (2-way = free on b128 reads).
__global__ __launch_bounds__(256, 1)
void xw_gemm(const float* __restrict__ x, const float* __restrict__ W,
             float* __restrict__ xw)
{
    __shared__ _Float16 Wl[HH * II];  // 64 KB
    const int tid  = threadIdx.x;
    const int l    = tid & 63;
    const int wv   = (__builtin_amdgcn_readfirstlane(tid) >> 6) & 3;
    const int lr   = l & 15;
    const int kgrp = l >> 4;

    // Stage W (row = output col n): f16, swizzled within each 256B row.
    {
        const int row = tid;
        const float4* src = (const float4*)(W + (size_t)row * II);
        unsigned* dst = (unsigned*)Wl;
        const int sw = (row & 7) << 4;
#pragma unroll
        for (int q = 0; q < II / 4; ++q) {
            float4 v = src[q];
            dst[(row * 256 + ((q * 8) ^ sw)) >> 2]     = pack2(v.x, v.y);
            dst[(row * 256 + ((q * 8 + 4) ^ sw)) >> 2] = pack2(v.z, v.w);
        }
    }
    __syncthreads();

    const size_t Mbase = (size_t)blockIdx.x * 64;
    const size_t arow  = Mbase + 16 * wv + lr;

    // A-fragments: x[arow][kc*32 + kgrp*8 .. +7] as f16
    f16x8 afr[4];
#pragma unroll
    for (int kc = 0; kc < 4; ++kc)
        afr[kc] = cvt8(x + arow * II + kc * 32 + kgrp * 8);

    f32x4 acc[16];
#pragma unroll
    for (int nt = 0; nt < 16; ++nt) acc[nt] = f32x4{0.f, 0.f, 0.f, 0.f};

#pragma unroll
    for (int nt = 0; nt < 16; ++nt) {
        const int col = nt * 16 + lr;
        const int sw  = (col & 7) << 4;
#pragma unroll
        for (int kc = 0; kc < 4; ++kc) {
            f16x8 bfr = *(const f16x8*)((const char*)Wl + col * 256 +
                                        ((kc * 64 + kgrp * 16) ^ sw));
            acc[nt] = __builtin_amdgcn_mfma_f32_16x16x32_f16(afr[kc], bfr, acc[nt], 0, 0, 0);
        }
    }
    // C layout (m89): col = l&15, row = (l>>4)*4 + r
#pragma unroll
    for (int nt = 0; nt < 16; ++nt) {
#pragma unroll
        for (int r = 0; r < 4; ++r) {
            size_t row = Mbase + 16 * wv + kgrp * 4 + r;
            xw[row * HH + nt * 16 + lr] = acc[nt][r];
        }
    }
}

// ---------------- Recurrence: h = tanh(xw[t] + h @ V^T + bias) -------------
// 64 WGs (batch rows 4g..4g+3, padded to M=16) x 512 thr (8 waves, 2/SIMD).
// Wave wv owns cols 32wv..32wv+31 (2 N-tiles). V-fragments permanent in regs.
// h-tile 16x256 f16 double-buffered in LDS, XOR-swizzled; ONE barrier/step.
// Reads xw fp32 from the seq region and overwrites it with h (same thread).
__global__ __launch_bounds__(512, 1)
void rnn_mfma(const float* __restrict__ bW, const float* __restrict__ V,
              const float* __restrict__ bV, float* __restrict__ out)
{
    __shared__ _Float16 hb[2 * 16 * HH];  // 16 KB, rows of 512 B, swizzled
    const int tid  = threadIdx.x;
    const int l    = tid & 63;
    const int wv   = (__builtin_amdgcn_readfirstlane(tid) >> 6) & 7;
    const int g    = blockIdx.x;   // batch rows 4g..4g+3
    const int lr   = l & 15;
    const int kgrp = l >> 4;

    // V-fragments: B[k][n] = V[n][k]; lane holds V[col][kc*32+kgrp*8 .. +7].
    f16x8 vfr[2][8];
    float biasc[2];
#pragma unroll
    for (int nt = 0; nt < 2; ++nt) {
        const int col = wv * 32 + nt * 16 + lr;
#pragma unroll
        for (int kc = 0; kc < 8; ++kc)
            vfr[nt][kc] = cvt8(V + (size_t)col * HH + kc * 32 + kgrp * 8);
        biasc[nt] = bW[col] + bV[col];
    }

    // Zero both h buffers (rows 4-15 stay zero forever = M padding).
    {
        unsigned* hz = (unsigned*)hb;
#pragma unroll
        for (int q = 0; q < 8; ++q) hz[tid + q * 512] = 0u;
    }
    __syncthreads();

    float* __restrict__ seq = out;                         // (T,B,H) fp32
    float* __restrict__ fin = out + (size_t)TT * BB * HH;  // (B,H) fp32

    // Prefetch xw[0] (lanes 0-15 hold rows r=0..3 per C-layout).
    float xwr[2][4];
    if (l < 16) {
#pragma unroll
        for (int nt = 0; nt < 2; ++nt)
#pragma unroll
            for (int r = 0; r < 4; ++r)
                xwr[nt][r] = seq[((size_t)0 * BB + 4 * g + r) * HH + wv * 32 + nt * 16 + lr];
    }

    int p = 0;
#pragma unroll 1
    for (int t = 0; t < TT; ++t) {
        // A-fragments: h[row=lr][kc*32 + kgrp*8 .. +7] from swizzled LDS.
        const char* hbase = (const char*)hb + p * 8192;
        f16x8 afr[8];
        const int sw = (lr & 7) << 4;
#pragma unroll
        for (int kc = 0; kc < 8; ++kc)
            afr[kc] = *(const f16x8*)(hbase + lr * 512 + ((kc * 64 + kgrp * 16) ^ sw));

        // Prefetch next xw (independent of h -> hides HBM latency under MFMA).
        float xwn[2][4];
        if (l < 16 && t + 1 < TT) {
#pragma unroll
            for (int nt = 0; nt < 2; ++nt)
#pragma unroll
                for (int r = 0; r < 4; ++r)
                    xwn[nt][r] = seq[((size_t)(t + 1) * BB + 4 * g + r) * HH + wv * 32 + nt * 16 + lr];
        }

        f32x4 acc0{0.f, 0.f, 0.f, 0.f}, acc1{0.f, 0.f, 0.f, 0.f};
#pragma unroll
        for (int kc = 0; kc < 8; ++kc) {
            acc0 = __builtin_amdgcn_mfma_f32_16x16x32_f16(afr[kc], vfr[0][kc], acc0, 0, 0, 0);
            acc1 = __builtin_amdgcn_mfma_f32_16x16x32_f16(afr[kc], vfr[1][kc], acc1, 0, 0, 0);
        }

        // Epilogue (lanes 0-15 hold the 4 real rows).
        char* wbase = (char*)hb + (p ^ 1) * 8192;
        if (l < 16) {
#pragma unroll
            for (int nt = 0; nt < 2; ++nt) {
                const int col = wv * 32 + nt * 16 + lr;
#pragma unroll
                for (int r = 0; r < 4; ++r) {
                    float a  = nt ? acc1[r] : acc0[r];
                    float hv = fast_tanh(a + xwr[nt][r] + biasc[nt]);
                    seq[((size_t)t * BB + 4 * g + r) * HH + col] = hv;  // overwrite xw
                    if (t == TT - 1) fin[(size_t)(4 * g + r) * HH + col] = hv;
                    *(_Float16*)(wbase + r * 512 + ((2 * col) ^ ((r & 7) << 4))) = (_Float16)hv;
                }
            }
#pragma unroll
            for (int nt = 0; nt < 2; ++nt)
#pragma unroll
                for (int r = 0; r < 4; ++r) xwr[nt][r] = xwn[nt][r];
        }

        LDS_BARRIER();  // h(t) visible; xw stores/loads stay in flight
        p ^= 1;
    }
}

extern "C" void kernel_launch(void* const* d_in, const int* in_sizes, int n_in,
                              void* d_out, int out_size, void* d_ws, size_t ws_size,
                              hipStream_t stream)
{
    const float* x  = (const float*)d_in[0];
    const float* W  = (const float*)d_in[1];
    const float* bW = (const float*)d_in[2];
    const float* V  = (const float*)d_in[3];
    const float* bV = (const float*)d_in[4];
    float* out = (float*)d_out;

    // Phase 1: xw = x @ W^T into the seq region of d_out (fp32).
    xw_gemm<<<dim3((TT * BB) / 64), dim3(256), 0, stream>>>(x, W, out);
    // Phase 2: serial recurrence, reading xw and overwriting with h.
    rnn_mfma<<<dim3(BB / 4), dim3(512), 0, stream>>>(bW, V, bV, out);
}